// Round 8
// baseline (5396.355 us; speedup 1.0000x reference)
//
#include <hip/hip_runtime.h>

// FPS: 2 batches x 131072 pts, 4096 samples/batch, seed = point 0.
// EXACT certified lookahead FPS, v3b: pipelined rendezvous, 8B key-only
// candidates, sort-based KW=16 wave extraction, tiered sim.
//
// r7 POST-MORTEM (absmax 161.5): under PIPELINED (stale) extraction the
// unconditional t=0 commit was UNSOUND - a wave's stale-inflated top-16
// can exclude the true global max, so "global max is in the pool" no
// longer holds. FIX: certify EVERY sim step (t=0 included) with a
// FULL-KEY test (wk > cutk). Soundness: any point outside the pool has
// exact key <= stale key < its wave-16th <= cutk, and sim scores only
// decrease; so winner key > cutk beats all outside points, idx tiebreak
// included (key order == (dist desc, idx asc)). If t=0 fails => j=0 =>
// pj=0 => NEXT round's extraction is exact, and then pool max == true
// global max with key > cutk (keys unique) => guaranteed commit. j=0
// never repeats consecutively - no livelock, bounded extra rounds.
//
//  * PIPELINE: extraction for round r uses dists stale by round r-1's
//    winners (update deferred until AFTER ship(r)). Staleness only
//    RAISES shipped dists/cutoff; sim FIXES pool copies by applying the
//    r-1 winners before simulating => pool values exact. fmin chains of
//    exact values => bit-exact.
//  * 8B candidates: key = dist_bits<<32 | r<<17 | (0x1FFFF - idx).
//    Coords re-fetched from read-only cached pts[idx].
//  * EXTRACT: per-lane Batcher-16 sort (63 CEs, compile-time indices ->
//    registers), then 16 DPP-tournament pops over lane heads (O(1)/pop).
//    cand 15 of each wave == its 16th-best == cut_w; cutoff = max over
//    128 waves of cut_w.
//  * SHIP: lanes 0..7 store one dwordx4 (2 cands), sys scope, unacked.
//    POLL: 4 batched dwordx4 loads/lane (one vmcnt), all-sys (the only
//    scope that resolves cross-CU on this part, r0-r4 evidence).
//  * PRUNE from poll regs: stale key > cutk -> wave-aggregated LDS
//    append. Pool SET is block-identical (order irrelevant: winners
//    found by u64 max).
//  * SIM: certified loop as above. Wave-register tier (NC=4/8/16 for
//    m<=256/512/1024, no barriers) or block tier (8/thread) for m<=2048.
//
// Ring safety (RING=2): a wave ships round r+1 (overwriting slot r-1)
// only after its poll(r) passed, which requires ALL 128 waves stored r,
// each of which happened after that wave's poll(r-1) finished reading
// slot r-1. Tags: bits 17-31 of each cand's lo word == r; zeroed or
// stale r-2 slots never match (r >= 1; r < 2^15 incl. j=0 rounds).

#define NB    32
#define TPB   256
#define PPT   16
#define NPB   131072
#define MSAMP 4096
#define RING  2
#define KW    16
#define NWAVE 128
#define NCAND (NWAVE * KW)      // 2048 candidates / round / batch
#define RBU32 (NCAND * 2)       // 4096 u32 = 16KB per ring slot
#define JCAP  64

typedef unsigned long long u64;
typedef unsigned int u32;
typedef __attribute__((ext_vector_type(4))) u32 u32x4;

__device__ __forceinline__ void st16_sys(u32* p, u32x4 v) {
  asm volatile("global_store_dwordx4 %0, %1, off sc0 sc1"
               :: "v"(p), "v"(v) : "memory");
}
// 4 poll loads issued back-to-back, ONE vmcnt drain (single RT).
__device__ __forceinline__ void ld16x4_sys(
    const u32* p0, const u32* p1, const u32* p2, const u32* p3,
    u32x4& q0, u32x4& q1, u32x4& q2, u32x4& q3) {
  asm volatile(
    "global_load_dwordx4 %0, %4, off sc0 sc1\n\t"
    "global_load_dwordx4 %1, %5, off sc0 sc1\n\t"
    "global_load_dwordx4 %2, %6, off sc0 sc1\n\t"
    "global_load_dwordx4 %3, %7, off sc0 sc1\n\t"
    "s_waitcnt vmcnt(0)"
    : "=v"(q0), "=v"(q1), "=v"(q2), "=v"(q3)
    : "v"(p0), "v"(p1), "v"(p2), "v"(p3)
    : "memory");
}

// ---- DPP helpers (proven r2-r6) ---------------------------------------
template<int CTRL>
__device__ __forceinline__ u64 dpp_move64(u64 x) {
  int lo = (int)(u32)(x & 0xFFFFFFFFull);
  int hi = (int)(u32)(x >> 32);
  int nlo = __builtin_amdgcn_update_dpp(lo, lo, CTRL, 0xF, 0xF, false);
  int nhi = __builtin_amdgcn_update_dpp(hi, hi, CTRL, 0xF, 0xF, false);
  return ((u64)(u32)nhi << 32) | (u64)(u32)nlo;
}
#define DPP_ROW_SHR(n)  (0x110 + (n))
#define DPP_BCAST15     0x142
#define DPP_BCAST31     0x143

__device__ __forceinline__ u64 dpp_max64_to63(u64 k) {
  u64 t;
  t = dpp_move64<DPP_ROW_SHR(1)>(k); if (t > k) k = t;
  t = dpp_move64<DPP_ROW_SHR(2)>(k); if (t > k) k = t;
  t = dpp_move64<DPP_ROW_SHR(4)>(k); if (t > k) k = t;
  t = dpp_move64<DPP_ROW_SHR(8)>(k); if (t > k) k = t;
  t = dpp_move64<DPP_BCAST15>(k);    if (t > k) k = t;
  t = dpp_move64<DPP_BCAST31>(k);    if (t > k) k = t;
  return k;                                   // lane63 = wave max
}
__device__ __forceinline__ u64 bcast_key(u64 k, int srclane) {
  u32 lo = (u32)__builtin_amdgcn_readlane((int)(u32)(k & 0xFFFFFFFFull), srclane);
  u32 hi = (u32)__builtin_amdgcn_readlane((int)(u32)(k >> 32), srclane);
  return ((u64)hi << 32) | (u64)lo;
}
__device__ __forceinline__ float bcast_f32(float v, int srclane) {
  return __uint_as_float((u32)__builtin_amdgcn_readlane((int)__float_as_uint(v), srclane));
}

struct BMax { u64 k; float x, y, z; };
__device__ __forceinline__ BMax block_max(u64 tk, float tx, float ty, float tz,
    int lane, int wv, int sb,
    u64* s_key, float* s_cx, float* s_cy, float* s_cz) {
  u64 wk = bcast_key(dpp_max64_to63(tk), 63);
  int wl = __ffsll(__ballot(tk == wk)) - 1;
  float wx = bcast_f32(tx, wl), wy = bcast_f32(ty, wl), wz = bcast_f32(tz, wl);
  if (lane == 0) { s_key[sb+wv]=wk; s_cx[sb+wv]=wx; s_cy[sb+wv]=wy; s_cz[sb+wv]=wz; }
  __syncthreads();
  u64 k0=s_key[sb],k1=s_key[sb+1],k2=s_key[sb+2],k3=s_key[sb+3];
  int bi=sb; u64 bk=k0;
  if (k1>bk){bk=k1;bi=sb+1;}
  if (k2>bk){bk=k2;bi=sb+2;}
  if (k3>bk){bk=k3;bi=sb+3;}
  BMax r; r.k=bk; r.x=s_cx[bi]; r.y=s_cy[bi]; r.z=s_cz[bi];
  return r;
}

// ---- wave-register sim: fix prev winners, then FULL-KEY certified loop -
template<int NC>
__device__ __forceinline__ int sim_wave(const u64* s_pool, int m, u64 cutk,
    int jmax, int lane, const float4* bpts,
    int pj, float pox, float poy, float poz,
    float& ox, float& oy, float& oz)
{
#pragma clang fp contract(off)
  u64 ck[NC]; float cx[NC], cy[NC], cz[NC];
#pragma unroll
  for (int i = 0; i < NC; ++i) {
    int idx = lane + i * 64;
    bool v = idx < m;
    u64 k = v ? s_pool[idx] : 0ull;
    int gi = v ? (int)(0x1FFFFu - (u32)(k & 0x1FFFFull)) : 0;
    float4 c = bpts[gi];
    ck[i] = k; cx[i] = c.y; cy[i] = c.z; cz[i] = c.w;
  }
  for (int t = 0; t < pj; ++t) {             // fix: apply prev winners
    float wx = bcast_f32(pox, t), wy = bcast_f32(poy, t), wz = bcast_f32(poz, t);
#pragma unroll
    for (int i = 0; i < NC; ++i) {
      float dx = cx[i]-wx, dy = cy[i]-wy, dz = cz[i]-wz;
      float d2 = __fadd_rn(__fadd_rn(__fmul_rn(dx,dx), __fmul_rn(dy,dy)),
                           __fmul_rn(dz,dz));
      float nd = fminf(__uint_as_float((u32)(ck[i] >> 32)), d2);
      ck[i] = ((u64)__float_as_uint(nd) << 32) | (ck[i] & 0xFFFFFFFFull);
    }
  }
  int j = 0;
  for (int t = 0; t < jmax; ++t) {
    u64 tk = ck[0]; float mx = cx[0], my = cy[0], mz = cz[0];
#pragma unroll
    for (int i = 1; i < NC; ++i)
      if (ck[i] > tk) { tk = ck[i]; mx = cx[i]; my = cy[i]; mz = cz[i]; }
    u64 wk = bcast_key(dpp_max64_to63(tk), 63);
    if (wk <= cutk) break;                   // FULL-KEY cert, ALL t (r7 fix)
    int wl = __ffsll(__ballot(tk == wk)) - 1;
    float wx = bcast_f32(mx, wl), wy = bcast_f32(my, wl), wz = bcast_f32(mz, wl);
    if (lane == t) { ox = wx; oy = wy; oz = wz; }
    j = t + 1;
#pragma unroll
    for (int i = 0; i < NC; ++i) {
      float dx = cx[i]-wx, dy = cy[i]-wy, dz = cz[i]-wz;
      float d2 = __fadd_rn(__fadd_rn(__fmul_rn(dx,dx), __fmul_rn(dy,dy)),
                           __fmul_rn(dz,dz));
      float nd = fminf(__uint_as_float((u32)(ck[i] >> 32)), d2);
      ck[i] = ((u64)__float_as_uint(nd) << 32) | (ck[i] & 0xFFFFFFFFull);
    }
  }
  return j;
}

// ---- block LDS sim (m <= 2048; exact; for large pools) ----------------
__device__ __forceinline__ int sim_block(const u64* s_pool, int m, u64 cutk,
    int jmax, int tid, int lane, int wv, int& sb, const float4* bpts,
    int pj, float pox, float poy, float poz,
    u64* s_key, float* s_cx, float* s_cy, float* s_cz, float (*s_win)[3])
{
#pragma clang fp contract(off)
  u64 ck[8]; float cx[8], cy[8], cz[8];
#pragma unroll
  for (int i = 0; i < 8; ++i) {
    int idx = tid + i * 256;
    bool v = idx < m;
    u64 k = v ? s_pool[idx] : 0ull;
    int gi = v ? (int)(0x1FFFFu - (u32)(k & 0x1FFFFull)) : 0;
    float4 c = bpts[gi];
    ck[i] = k; cx[i] = c.y; cy[i] = c.z; cz[i] = c.w;
  }
  for (int t = 0; t < pj; ++t) {
    float wx = bcast_f32(pox, t), wy = bcast_f32(poy, t), wz = bcast_f32(poz, t);
#pragma unroll
    for (int i = 0; i < 8; ++i) {
      float dx = cx[i]-wx, dy = cy[i]-wy, dz = cz[i]-wz;
      float d2 = __fadd_rn(__fadd_rn(__fmul_rn(dx,dx), __fmul_rn(dy,dy)),
                           __fmul_rn(dz,dz));
      float nd = fminf(__uint_as_float((u32)(ck[i] >> 32)), d2);
      ck[i] = ((u64)__float_as_uint(nd) << 32) | (ck[i] & 0xFFFFFFFFull);
    }
  }
  int j = 0;
  for (int t = 0; t < jmax; ++t) {
    u64 tk = ck[0]; float mx = cx[0], my = cy[0], mz = cz[0];
#pragma unroll
    for (int i = 1; i < 8; ++i)
      if (ck[i] > tk) { tk = ck[i]; mx = cx[i]; my = cy[i]; mz = cz[i]; }
    BMax w = block_max(tk, mx, my, mz, lane, wv, sb, s_key, s_cx, s_cy, s_cz);
    sb ^= 4;
    if (w.k <= cutk) break;                  // FULL-KEY cert, ALL t (r7 fix)
    if (tid == 0) { s_win[t][0]=w.x; s_win[t][1]=w.y; s_win[t][2]=w.z; }
    j = t + 1;
#pragma unroll
    for (int i = 0; i < 8; ++i) {
      float dx = cx[i]-w.x, dy = cy[i]-w.y, dz = cz[i]-w.z;
      float d2 = __fadd_rn(__fadd_rn(__fmul_rn(dx,dx), __fmul_rn(dy,dy)),
                           __fmul_rn(dz,dz));
      float nd = fminf(__uint_as_float((u32)(ck[i] >> 32)), d2);
      ck[i] = ((u64)__float_as_uint(nd) << 32) | (ck[i] & 0xFFFFFFFFull);
    }
  }
  __syncthreads();                           // s_win visible
  return j;
}

#define CE(a,b) { if (sk[a] < sk[b]) { u64 t_ = sk[a]; sk[a] = sk[b]; sk[b] = t_; } }

__global__ __launch_bounds__(TPB, 1)
void fps_kernel(const float4* __restrict__ pts, float* __restrict__ out,
                u32* __restrict__ slots)
{
#pragma clang fp contract(off)
  const int batch = blockIdx.x >> 5;
  const int rank  = blockIdx.x & (NB - 1);
  const int tid   = threadIdx.x;
  const int lane  = tid & 63;
  const int wv    = tid >> 6;
  const int ws_id = rank * 4 + wv;           // wave-slot 0..127

  __shared__ u64   s_pool[NCAND];
  __shared__ u64   s_cutq[4];
  __shared__ float s_win[JCAP][3];
  __shared__ u64   s_key[8];
  __shared__ float s_cx[8], s_cy[8], s_cz[8];
  __shared__ int   s_cnt2[2];

  const float4* bpts = pts + (size_t)batch * NPB;
  u32* bslots = slots + (size_t)batch * (RING * RBU32);
  const int base = rank * (TPB * PPT);

  float px[PPT], py[PPT], pz[PPT], dist[PPT];
  float4 seed = bpts[0];
  const float sx = seed.y, sy = seed.z, sz = seed.w;
#pragma unroll
  for (int k = 0; k < PPT; ++k) {
    float4 p = bpts[base + k * TPB + tid];   // row = (b, x, y, z)
    px[k] = p.y; py[k] = p.z; pz[k] = p.w;
    float dx = px[k]-sx, dy = py[k]-sy, dz = pz[k]-sz;
    dist[k] = __fadd_rn(__fadd_rn(__fmul_rn(dx,dx), __fmul_rn(dy,dy)),
                        __fmul_rn(dz,dz));   // == reference dist init
  }
  if (rank == 0 && tid == 0) {
    float4 o; o.x=(float)batch; o.y=sx; o.z=sy; o.w=sz;
    *(float4*)(out + (size_t)batch * MSAMP * 4) = o;
  }
  if (tid == 0) { s_cnt2[0] = 0; s_cnt2[1] = 0; }
  __syncthreads();

  int S = 0; u32 r = 0; int sb = 0;
  int pj = 0; float pox = 0.f, poy = 0.f, poz = 0.f;  // prev-round winners
  float ox = 0.f, oy = 0.f, oz = 0.f;

  while (S < MSAMP - 1) {
    r += 1;
    const int rem = (MSAMP - 1) - S;
    const int jmax = (rem < JCAP) ? rem : JCAP;

    // ---- EXTRACT (dists stale by pj prev winners, by design) ----
    u64 sk[16];
#pragma unroll
    for (int k = 0; k < PPT; ++k)
      sk[k] = ((u64)__float_as_uint(dist[k]) << 32) | ((u64)r << 17) |
              (u64)(0x1FFFFu - (u32)(base + k * TPB + tid));
    // Batcher odd-even mergesort, 16 elems, descending (63 CEs)
    CE(0,1) CE(2,3) CE(4,5) CE(6,7) CE(8,9) CE(10,11) CE(12,13) CE(14,15)
    CE(0,2) CE(1,3) CE(4,6) CE(5,7) CE(8,10) CE(9,11) CE(12,14) CE(13,15)
    CE(1,2) CE(5,6) CE(9,10) CE(13,14)
    CE(0,4) CE(1,5) CE(2,6) CE(3,7) CE(8,12) CE(9,13) CE(10,14) CE(11,15)
    CE(2,4) CE(3,5) CE(10,12) CE(11,13)
    CE(1,2) CE(3,4) CE(5,6) CE(9,10) CE(11,12) CE(13,14)
    CE(0,8) CE(1,9) CE(2,10) CE(3,11) CE(4,12) CE(5,13) CE(6,14) CE(7,15)
    CE(4,8) CE(5,9) CE(6,10) CE(7,11)
    CE(2,4) CE(3,5) CE(6,8) CE(7,9) CE(10,12) CE(11,13)
    CE(1,2) CE(3,4) CE(5,6) CE(7,8) CE(9,10) CE(11,12) CE(13,14)

    u32x4 shipq; shipq.x = shipq.y = shipq.z = shipq.w = 0u;
#pragma unroll
    for (int c = 0; c < KW; ++c) {           // 16 pops, O(1) each
      u64 wk = bcast_key(dpp_max64_to63(sk[0]), 63);
      if (sk[0] == wk) {                     // unique winner shifts list
#pragma unroll
        for (int i = 0; i < 15; ++i) sk[i] = sk[i+1];
        sk[15] = 0ull;
      }
      u32 lo = (u32)(wk & 0xFFFFFFFFull), hi = (u32)(wk >> 32);
      if (lane == (c >> 1)) {
        if (c & 1) { shipq.z = lo; shipq.w = hi; }
        else       { shipq.x = lo; shipq.y = hi; }
      }
    }

    // ---- SHIP: 8 lanes x dwordx4 (2 cands each), unacked ----
    u32* ring = bslots + (size_t)(r & 1u) * RBU32;
    if (lane < 8) st16_sys(ring + (ws_id * 16 + lane * 2) * 2, shipq);

    // ---- UPDATE prev winners (hides store flight) ----
    for (int t = 0; t < pj; ++t) {
      float wx = bcast_f32(pox, t), wy = bcast_f32(poy, t), wz = bcast_f32(poz, t);
#pragma unroll
      for (int k = 0; k < PPT; ++k) {
        float dx = px[k]-wx, dy = py[k]-wy, dz = pz[k]-wz;
        float d2 = __fadd_rn(__fadd_rn(__fmul_rn(dx,dx), __fmul_rn(dy,dy)),
                             __fmul_rn(dz,dz));
        dist[k] = fminf(dist[k], d2);
      }
    }

    // ---- POLL: wave's 512-cand quarter, 4 batched loads/lane ----
    const int cb = wv * 512 + lane * 2;
    const u32 *P0 = ring + (cb      ) * 2, *P1 = ring + (cb + 128) * 2,
              *P2 = ring + (cb + 256) * 2, *P3 = ring + (cb + 384) * 2;
    u32x4 q0, q1, q2, q3;
    for (;;) {
      ld16x4_sys(P0, P1, P2, P3, q0, q1, q2, q3);
      bool ok = ((q0.x>>17)==r) && ((q0.z>>17)==r) && ((q1.x>>17)==r) &&
                ((q1.z>>17)==r) && ((q2.x>>17)==r) && ((q2.z>>17)==r) &&
                ((q3.x>>17)==r) && ((q3.z>>17)==r);
      if (__ballot(ok) == ~0ull) break;
      __builtin_amdgcn_s_sleep(1);
    }

    // ---- CUTOFF: cand c%16==15 == wave cut; held by lanes L%8==7 (odd half)
    u64 cm = 0ull;
    if ((lane & 7) == 7) {
      u64 a0 = ((u64)q0.w << 32) | (u64)q0.z;
      u64 a1 = ((u64)q1.w << 32) | (u64)q1.z;
      u64 a2 = ((u64)q2.w << 32) | (u64)q2.z;
      u64 a3 = ((u64)q3.w << 32) | (u64)q3.z;
      cm = a0; if (a1 > cm) cm = a1; if (a2 > cm) cm = a2; if (a3 > cm) cm = a3;
    }
    u64 qc = bcast_key(dpp_max64_to63(cm), 63);
    if (lane == 0) s_cutq[wv] = qc;
    __syncthreads();                         // barrier A
    u64 cutk = s_cutq[0];
    if (s_cutq[1] > cutk) cutk = s_cutq[1];
    if (s_cutq[2] > cutk) cutk = s_cutq[2];
    if (s_cutq[3] > cutk) cutk = s_cutq[3];
    if (tid == 0) s_cnt2[(r + 1) & 1] = 0;   // reset next round's counter

    // ---- PRUNE from poll regs (wave-aggregated LDS append) ----
    u64 kk[8] = { ((u64)q0.y<<32)|q0.x, ((u64)q0.w<<32)|q0.z,
                  ((u64)q1.y<<32)|q1.x, ((u64)q1.w<<32)|q1.z,
                  ((u64)q2.y<<32)|q2.x, ((u64)q2.w<<32)|q2.z,
                  ((u64)q3.y<<32)|q3.x, ((u64)q3.w<<32)|q3.z };
    bool hh[8]; int myoff[8]; int tot = 0;
    const u64 ltmask = (lane == 63) ? ~0ull >> 1 : ((1ull << lane) - 1ull);
#pragma unroll
    for (int i = 0; i < 8; ++i) {
      hh[i] = kk[i] > cutk;
      u64 b = __ballot(hh[i]);
      myoff[i] = tot + __popcll(b & ltmask);
      tot += __popcll(b);
    }
    int pbase = 0;
    if (lane == 0) pbase = atomicAdd(&s_cnt2[r & 1], tot);
    pbase = __builtin_amdgcn_readfirstlane(pbase);
#pragma unroll
    for (int i = 0; i < 8; ++i)
      if (hh[i]) s_pool[pbase + myoff[i]] = kk[i];
    __syncthreads();                         // barrier B
    const int m = s_cnt2[r & 1];

    // ---- SIM (tiered; fixes pool with pj prev winners first) ----
    int j;
    if (m <= 256)
      j = sim_wave<4>(s_pool, m, cutk, jmax, lane, bpts, pj, pox, poy, poz, ox, oy, oz);
    else if (m <= 512)
      j = sim_wave<8>(s_pool, m, cutk, jmax, lane, bpts, pj, pox, poy, poz, ox, oy, oz);
    else if (m <= 1024)
      j = sim_wave<16>(s_pool, m, cutk, jmax, lane, bpts, pj, pox, poy, poz, ox, oy, oz);
    else {
      j = sim_block(s_pool, m, cutk, jmax, tid, lane, wv, sb, bpts,
                    pj, pox, poy, poz, s_key, s_cx, s_cy, s_cz, s_win);
      if (lane < j) { ox = s_win[lane][0]; oy = s_win[lane][1]; oz = s_win[lane][2]; }
    }

    // ---- COMMIT rows; defer reg-dist update to next iteration ----
    if (rank == 0 && wv == 0 && lane < j) {
      float4 o; o.x = (float)batch; o.y = ox; o.z = oy; o.w = oz;
      *(float4*)(out + (size_t)(batch * MSAMP + S + 1 + lane) * 4) = o;
    }
    S += j; pj = j; pox = ox; poy = oy; poz = oz;
  }
}

extern "C" void kernel_launch(void* const* d_in, const int* in_sizes, int n_in,
                              void* d_out, int out_size, void* d_ws, size_t ws_size,
                              hipStream_t stream) {
  const float4* pts = (const float4*)d_in[0];
  float* out = (float*)d_out;
  u32* slots = (u32*)d_ws;

  // Zero both batches' rings (64 KB): stale tags can never validate.
  hipMemsetAsync(d_ws, 0, (size_t)2 * RING * RBU32 * 4, stream);

  dim3 grid(2 * NB), block(TPB);
  hipLaunchKernelGGL(fps_kernel, grid, block, 0, stream, pts, out, slots);
}